// Round 14
// baseline (362.572 us; speedup 1.0000x reference)
//
#include <hip/hip_runtime.h>
#include <stdint.h>
#include <math.h>

#define HW   4096
#define NB   8
#define NC   512
#define C2   256
#define QC   256    // q-chunk per block (4 k per lane via one float4)
#define NTG  32     // tile-groups of 4 tiles (n1 = 1024 -> 128 tiles of 8)
#define NCH  12     // q-chunks (n0 = 3072 for this fixed flag)

// ---------- ws layout (bytes) ----------
#define WS_PACKED 0         // u64 packed[8*4096]            = 262144
#define WS_Q0     393216    // i32 q0list[4096]              = 16384
#define WS_P1     409600    // i32 p1list[4096]              = 16384
#define WS_CNT    425984    // i32 cnt[2]
#define WS_INVC   558080    // f32 invc[8*4096]              = 131072

__device__ __forceinline__ unsigned long long mkkey(float v, unsigned q) {
    unsigned u = __float_as_uint(v);
    u = (u & 0x80000000u) ? ~u : (u | 0x80000000u);   // monotone float -> u32
    return ((unsigned long long)u << 32) | (unsigned long long)(0xFFFFFFFFu - q);
}

// Packed scratch lives in d_out's shift region (channels [512,768) of batch b)
// = 1M floats per batch: lfc (C2 x ns) then ffc (C2 x ms). Written by
// pack_kernel, read by invc/argmax, then fully overwritten by shift_kernel.
__device__ __forceinline__ float* lfc_region(float* out, int b) {
    return out + ((size_t)b * 768 + 512) * HW;
}

// --- 1. deterministic sorted compaction of flag into p1 (flag==1) / q0 (flag==0)
__global__ void compact_kernel(const int* __restrict__ flag, int* __restrict__ q0,
                               int* __restrict__ p1, int* __restrict__ cnt) {
    __shared__ int c1s[256];
    int t = threadIdx.x;
    int f[16]; int n1 = 0;
    #pragma unroll
    for (int j = 0; j < 16; ++j) { f[j] = flag[t*16 + j]; n1 += (f[j] == 1); }
    c1s[t] = n1;
    __syncthreads();
    if (t == 0) {
        int run = 0;
        for (int i = 0; i < 256; ++i) { int v = c1s[i]; c1s[i] = run; run += v; }
        cnt[0] = run;          // n1
        cnt[1] = HW - run;     // n0
    }
    __syncthreads();
    int b1 = c1s[t];
    int b0 = t*16 - c1s[t];
    for (int j = 0; j < 16; ++j) {
        int i = t*16 + j;
        if (f[j] == 1) p1[b1++] = i; else q0[b0++] = i;
    }
}

// --- 2. fused copy + pack. Block (b, cy) reads row x[b][cy] once:
//     - coalesced copy: out[b][cy][i] = x[b][cy][i]
//     - cy <  256 (former): ffc[cy][m] = xrow[p1[m]]
//     - cy >= 256 (latter): lfc[cy-256][k] = xrow[q0[k]]
__global__ void pack_kernel(const float* __restrict__ x,
                            const int* __restrict__ q0, const int* __restrict__ p1,
                            const int* __restrict__ cnt, float* __restrict__ out) {
    int b = blockIdx.z, cy = blockIdx.y;
    int i = blockIdx.x * 256 + threadIdx.x;
    int n1 = cnt[0], n0 = cnt[1];
    int ns = (n0 + 3) & ~3, ms = (n1 + 3) & ~3;
    const float* xrow = x + ((size_t)b * NC + cy) * HW;
    out[((size_t)b * 768 + cy) * HW + i] = xrow[i];      // fused copy
    if (cy < C2) {
        if (i < n1) {
            float* ffc = lfc_region(out, b) + (size_t)C2 * ns;
            ffc[(size_t)cy * ms + i] = xrow[p1[i]];
        }
    } else {
        int c = cy - C2;
        if (i < n0) {
            float* lfc = lfc_region(out, b);
            lfc[(size_t)c * ns + i] = xrow[q0[i]];
        }
    }
}

// --- 2b. invc from packed lfc (coalesced; same c-ascending fp32 sum order
//     as the original norm kernel -> bit-identical values at q0 columns)
__global__ void invc_kernel(const float* __restrict__ out, const int* __restrict__ cnt,
                            float* __restrict__ invc) {
    int b = blockIdx.y;
    int n0 = cnt[1];
    int ns = (n0 + 3) & ~3;
    int k = blockIdx.x * 256 + threadIdx.x;
    if (k >= n0) return;
    const float* lfc = lfc_region((float*)out, b) + k;
    float s = 0.f;
    #pragma unroll 8
    for (int c = 0; c < C2; ++c) {
        float v = lfc[(size_t)c * ns];
        s = fmaf(v, v, s);
    }
    invc[b * HW + k] = 1.0f / fmaxf(sqrtf(s), 1e-8f);
}

// one c-row of FMAs: 8 p (wave-uniform, from A0/A1) x 4 k (per-lane float4 F)
#define ROWF(A0, A1, F) {                                                 \
    float av[8] = {A0.x, A0.y, A0.z, A0.w, A1.x, A1.y, A1.z, A1.w};       \
    float bv[4] = {F.x, F.y, F.z, F.w};                                   \
    _Pragma("unroll")                                                     \
    for (int pi = 0; pi < 8; ++pi) {                                      \
        _Pragma("unroll")                                                 \
        for (int j = 0; j < 4; ++j)                                       \
            acc[pi][j] = fmaf(av[pi], bv[j], acc[pi][j]);                 \
    } }

#define LDA(A0, A1, C) { const float* fa_ = fb + (size_t)(C) * ms;        \
    A0 = *(const float4*)fa_; A1 = *(const float4*)(fa_ + 4); }
#define LDF(F, C) F = *(const float4*)(rb + (size_t)(C) * ns);

// --- 3. cos + argmax, LDS-free, 4 waves/block sharing one lf chunk.
//     R13 found a ~16 workgroup/CU cap: 1-wave blocks pin occupancy at 50%.
//     Fix: 256-thread blocks of 4 INDEPENDENT waves (no LDS, no barriers);
//     all 4 waves read the SAME lf chunk rows (L1 reuse: lf L2 traffic /4,
//     was ~1.5 GB ~ 96us at 34.5 TB/s — same order as the 82us FMA floor),
//     each wave its own 8-p tile (tile = tg*4 + waveid).
//     Per row per lane: 32 FMA + 1 float4 lf + 2 float4 ff (uniform).
//     Rotation-free depth-4 prefetch (R11/R13). bid&7 = batch -> XCD pin
//     (4MB lfc+ffc per batch in one XCD L2; R9: FETCH 148->16.6MB).
//     NOTE: no min-waves clamp in launch_bounds — (256,4) forced VGPR=64
//     and spilled acc to scratch (13 GB HBM, 7x regression in R3).
__global__ void __launch_bounds__(256) argmax_kernel(
        float* __restrict__ out, const float* __restrict__ invc,
        const int* __restrict__ q0, const int* __restrict__ p1,
        const int* __restrict__ cnt, unsigned long long* __restrict__ packed) {
    int bid   = blockIdx.x;
    int b     = bid & 7;
    int s     = bid >> 3;
    int tg    = s & (NTG - 1);
    int chunk = s >> 5;
    int n1 = cnt[0], n0 = cnt[1];
    if (chunk * QC >= n0) return;
    int wid  = threadIdx.x >> 6;            // wave 0..3
    int lane = threadIdx.x & 63;
    int tile = tg * 4 + wid;
    if (tile * 8 >= n1) return;             // per-wave exit, no barriers
    int ns = (n0 + 3) & ~3, ms = (n1 + 3) & ~3;

    const float* lfc = lfc_region(out, b);
    const float* ffc = lfc + (size_t)C2 * ns;
    int kbase = chunk * QC + lane * 4;      // 16B aligned, same for all waves

    const float* fb = ffc + tile * 8;       // wave-uniform base
    const float* rb = lfc + kbase;          // per-lane base (shared across waves)

    float4 aA0, aA1, aB0, aB1, aC0, aC1, aD0, aD1;
    float4 f0, f1, f2, f3;
    LDA(aA0, aA1, 0) LDA(aB0, aB1, 1) LDA(aC0, aC1, 2) LDA(aD0, aD1, 3)
    LDF(f0, 0) LDF(f1, 1) LDF(f2, 2) LDF(f3, 3)

    float acc[8][4];
    #pragma unroll
    for (int pi = 0; pi < 8; ++pi)
        #pragma unroll
        for (int j = 0; j < 4; ++j) acc[pi][j] = 0.f;

    int cc = 0;
    for (; cc < C2 - 4; cc += 4) {
        ROWF(aA0, aA1, f0); LDA(aA0, aA1, cc + 4); LDF(f0, cc + 4);
        ROWF(aB0, aB1, f1); LDA(aB0, aB1, cc + 5); LDF(f1, cc + 5);
        ROWF(aC0, aC1, f2); LDA(aC0, aC1, cc + 6); LDF(f2, cc + 6);
        ROWF(aD0, aD1, f3); LDA(aD0, aD1, cc + 7); LDF(f3, cc + 7);
    }
    ROWF(aA0, aA1, f0); ROWF(aB0, aB1, f1);
    ROWF(aC0, aC1, f2); ROWF(aD0, aD1, f3);

    float best[8];
    int   bq[8];
    #pragma unroll
    for (int pi = 0; pi < 8; ++pi) { best[pi] = -INFINITY; bq[pi] = 0x7FFFFFFF; }

    #pragma unroll
    for (int j = 0; j < 4; ++j) {
        int k = kbase + j;
        if (k >= n0) continue;
        float sc = invc[b * HW + k];
        int   q  = q0[k];
        #pragma unroll
        for (int pi = 0; pi < 8; ++pi) {
            float cv = acc[pi][j] * sc;
            if (cv > best[pi] || (cv == best[pi] && q < bq[pi])) {
                best[pi] = cv; bq[pi] = q;
            }
        }
    }

    // wave reduce (all 64 lanes of this wave share the same 8 p's)
    #pragma unroll
    for (int m = 1; m < 64; m <<= 1) {
        #pragma unroll
        for (int pi = 0; pi < 8; ++pi) {
            float ov = __shfl_xor(best[pi], m);
            int   oq = __shfl_xor(bq[pi], m);
            if (ov > best[pi] || (ov == best[pi] && oq < bq[pi])) {
                best[pi] = ov; bq[pi] = oq;
            }
        }
    }
    if (lane == 0) {
        #pragma unroll
        for (int pi = 0; pi < 8; ++pi) {
            int pidx = tile * 8 + pi;
            int p = (pidx < n1) ? p1[pidx] : -1;
            if (p >= 0)
                atomicMax(&packed[(size_t)b * HW + p], mkkey(best[pi], (unsigned)bq[pi]));
        }
    }
}

// --- 4. shift writeback with inline decode:
//     out[b, 512+c, p] = flag[p] ? lf[b, c, argmax_q(packed)] : 0
//     (fully overwrites the lfc/ffc scratch region — must run after argmax)
__global__ void shift_kernel(const float* __restrict__ x, const int* __restrict__ flag,
                             const unsigned long long* __restrict__ packed,
                             float* __restrict__ out) {
    int cc = blockIdx.x, b = blockIdx.y;
    const float* lfrow = x + ((size_t)b * NC + C2 + cc) * HW;
    float*       orow  = out + ((size_t)b * 768 + 512 + cc) * HW;
    const unsigned long long* pk = packed + (size_t)b * HW;
    for (int p = threadIdx.x; p < HW; p += 256) {
        float v = 0.f;
        if (flag[p] == 1) {
            unsigned low = (unsigned)(pk[p] & 0xFFFFFFFFull);
            int q = (int)((0xFFFFFFFFu - low) & (HW - 1));
            v = lfrow[q];
        }
        orow[p] = v;
    }
}

extern "C" void kernel_launch(void* const* d_in, const int* in_sizes, int n_in,
                              void* d_out, int out_size, void* d_ws, size_t ws_size,
                              hipStream_t stream) {
    const float* x    = (const float*)d_in[0];
    const int*   flag = (const int*)d_in[1];
    float*       out  = (float*)d_out;
    char*        ws   = (char*)d_ws;

    unsigned long long* packed = (unsigned long long*)(ws + WS_PACKED);
    int*   q0   = (int*)(ws + WS_Q0);
    int*   p1   = (int*)(ws + WS_P1);
    int*   cnt  = (int*)(ws + WS_CNT);
    float* invc = (float*)(ws + WS_INVC);

    hipMemsetAsync(packed, 0, (size_t)NB * HW * sizeof(unsigned long long), stream);

    compact_kernel<<<1, 256, 0, stream>>>(flag, q0, p1, cnt);
    pack_kernel<<<dim3(HW / 256, NC, NB), 256, 0, stream>>>(x, q0, p1, cnt, out);
    invc_kernel<<<dim3(HW / 256, NB), 256, 0, stream>>>(out, cnt, invc);
    argmax_kernel<<<dim3(NB * NTG * NCH), 256, 0, stream>>>(out, invc, q0, p1, cnt, packed);
    shift_kernel<<<dim3(C2, NB), 256, 0, stream>>>(x, flag, packed, out);
}

// Round 15
// 261.578 us; speedup vs baseline: 1.3861x; 1.3861x over previous
//
#include <hip/hip_runtime.h>
#include <stdint.h>
#include <math.h>

#define HW   4096
#define NB   8
#define NC   512
#define C2   256
#define QC   256    // q-chunk per wave (4 k per lane via one float4)
#define NT1  128    // p-tiles of 8 (n1 = 1024 for this fixed flag)
#define NPR  6      // chunk-pairs (12 chunks / 2 waves); dead waves exit

// ---------- ws layout (bytes) ----------
#define WS_PACKED 0         // u64 packed[8*4096]            = 262144
#define WS_Q0     393216    // i32 q0list[4096]              = 16384
#define WS_P1     409600    // i32 p1list[4096]              = 16384
#define WS_CNT    425984    // i32 cnt[2]
#define WS_INVC   558080    // f32 invc[8*4096]              = 131072

__device__ __forceinline__ unsigned long long mkkey(float v, unsigned q) {
    unsigned u = __float_as_uint(v);
    u = (u & 0x80000000u) ? ~u : (u | 0x80000000u);   // monotone float -> u32
    return ((unsigned long long)u << 32) | (unsigned long long)(0xFFFFFFFFu - q);
}

// Packed scratch lives in d_out's shift region (channels [512,768) of batch b)
// = 1M floats per batch: lfc (C2 x ns) then ffc (C2 x ms). Written by
// pack_kernel, read by invc/argmax, then fully overwritten by shift_kernel.
__device__ __forceinline__ float* lfc_region(float* out, int b) {
    return out + ((size_t)b * 768 + 512) * HW;
}

// --- 1. deterministic sorted compaction of flag into p1 (flag==1) / q0 (flag==0)
__global__ void compact_kernel(const int* __restrict__ flag, int* __restrict__ q0,
                               int* __restrict__ p1, int* __restrict__ cnt) {
    __shared__ int c1s[256];
    int t = threadIdx.x;
    int f[16]; int n1 = 0;
    #pragma unroll
    for (int j = 0; j < 16; ++j) { f[j] = flag[t*16 + j]; n1 += (f[j] == 1); }
    c1s[t] = n1;
    __syncthreads();
    if (t == 0) {
        int run = 0;
        for (int i = 0; i < 256; ++i) { int v = c1s[i]; c1s[i] = run; run += v; }
        cnt[0] = run;          // n1
        cnt[1] = HW - run;     // n0
    }
    __syncthreads();
    int b1 = c1s[t];
    int b0 = t*16 - c1s[t];
    for (int j = 0; j < 16; ++j) {
        int i = t*16 + j;
        if (f[j] == 1) p1[b1++] = i; else q0[b0++] = i;
    }
}

// --- 2. fused copy + pack. Block (b, cy) reads row x[b][cy] once:
//     - coalesced copy: out[b][cy][i] = x[b][cy][i]
//     - cy <  256 (former): ffc[cy][m] = xrow[p1[m]]
//     - cy >= 256 (latter): lfc[cy-256][k] = xrow[q0[k]]
__global__ void pack_kernel(const float* __restrict__ x,
                            const int* __restrict__ q0, const int* __restrict__ p1,
                            const int* __restrict__ cnt, float* __restrict__ out) {
    int b = blockIdx.z, cy = blockIdx.y;
    int i = blockIdx.x * 256 + threadIdx.x;
    int n1 = cnt[0], n0 = cnt[1];
    int ns = (n0 + 3) & ~3, ms = (n1 + 3) & ~3;
    const float* xrow = x + ((size_t)b * NC + cy) * HW;
    out[((size_t)b * 768 + cy) * HW + i] = xrow[i];      // fused copy
    if (cy < C2) {
        if (i < n1) {
            float* ffc = lfc_region(out, b) + (size_t)C2 * ns;
            ffc[(size_t)cy * ms + i] = xrow[p1[i]];
        }
    } else {
        int c = cy - C2;
        if (i < n0) {
            float* lfc = lfc_region(out, b);
            lfc[(size_t)c * ns + i] = xrow[q0[i]];
        }
    }
}

// --- 2b. invc from packed lfc (coalesced; same c-ascending fp32 sum order
//     as the original norm kernel -> bit-identical values at q0 columns)
__global__ void invc_kernel(const float* __restrict__ out, const int* __restrict__ cnt,
                            float* __restrict__ invc) {
    int b = blockIdx.y;
    int n0 = cnt[1];
    int ns = (n0 + 3) & ~3;
    int k = blockIdx.x * 256 + threadIdx.x;
    if (k >= n0) return;
    const float* lfc = lfc_region((float*)out, b) + k;
    float s = 0.f;
    #pragma unroll 8
    for (int c = 0; c < C2; ++c) {
        float v = lfc[(size_t)c * ns];
        s = fmaf(v, v, s);
    }
    invc[b * HW + k] = 1.0f / fmaxf(sqrtf(s), 1e-8f);
}

// one c-row of FMAs: 8 p (wave-uniform, SGPR) x 4 k (per-lane float4 F)
#define ROWF(A0, A1, F) {                                                 \
    float av[8] = {A0.x, A0.y, A0.z, A0.w, A1.x, A1.y, A1.z, A1.w};       \
    float bv[4] = {F.x, F.y, F.z, F.w};                                   \
    _Pragma("unroll")                                                     \
    for (int pi = 0; pi < 8; ++pi) {                                      \
        _Pragma("unroll")                                                 \
        for (int j = 0; j < 4; ++j)                                       \
            acc[pi][j] = fmaf(av[pi], bv[j], acc[pi][j]);                 \
    } }

// ff: block-uniform base -> scalar s_load (zero VALU)
#define LDA(A0, A1, C) { const float* fa_ = fb + (size_t)(C) * ms;        \
    A0 = *(const float4*)fa_; A1 = *(const float4*)(fa_ + 4); }
// lf: UNIFORM row pointer + constant per-lane 32-bit offset -> saddr-form
// global_load, row advance on the scalar pipe (R13 kept a per-lane 64-bit
// pointer -> 2 VALU add/addc per row)
#define LDF(F, C) { const float* rp_ = lfc + (size_t)(C) * ns;            \
    F = *(const float4*)(rp_ + koff); }

// --- 3. cos + argmax, LDS-free, 2 waves/block: SAME tile (blockIdx-only ->
//     ff stays provably wave-uniform -> s_load; R14 lesson: tile from
//     threadIdx kills the scalar pipe), DIFFERENT chunk per wave.
//     16 resident blocks x 2 waves = 32 waves/CU, beating the 16-wg/CU cap
//     that pinned R13's 1-wave blocks at 50% occupancy.
//     Per row per lane: 32 FMA + 1 saddr float4 (lf) + uniform 32B (ff).
//     Rotation-free depth-4 prefetch. bid&7 = batch -> XCD pin (4MB
//     lfc+ffc per batch in one XCD L2; R9: FETCH 148->16.6MB).
//     NOTE: no min-waves clamp in launch_bounds — (256,4) forced VGPR=64
//     and spilled acc to scratch (13 GB HBM, 7x regression in R3).
__global__ void __launch_bounds__(128) argmax_kernel(
        float* __restrict__ out, const float* __restrict__ invc,
        const int* __restrict__ q0, const int* __restrict__ p1,
        const int* __restrict__ cnt, unsigned long long* __restrict__ packed) {
    int bid   = blockIdx.x;
    int b     = bid & 7;
    int s     = bid >> 3;
    int tile  = s & (NT1 - 1);          // blockIdx-only -> wave-uniform
    int pair  = s >> 7;
    int n1 = cnt[0], n0 = cnt[1];
    if (tile * 8 >= n1) return;
    int wid  = threadIdx.x >> 6;        // 0..1
    int lane = threadIdx.x & 63;
    int chunk = pair * 2 + wid;
    if (chunk * QC >= n0) return;       // per-wave exit; no barriers anywhere
    int ns = (n0 + 3) & ~3, ms = (n1 + 3) & ~3;

    const float* lfc = lfc_region(out, b);
    const float* ffc = lfc + (size_t)C2 * ns;
    int koff = chunk * QC + lane * 4;   // element offset, constant per lane

    const float* fb = ffc + tile * 8;   // block-uniform base

    float4 aA0, aA1, aB0, aB1, aC0, aC1, aD0, aD1;
    float4 f0, f1, f2, f3;
    LDA(aA0, aA1, 0) LDA(aB0, aB1, 1) LDA(aC0, aC1, 2) LDA(aD0, aD1, 3)
    LDF(f0, 0) LDF(f1, 1) LDF(f2, 2) LDF(f3, 3)

    float acc[8][4];
    #pragma unroll
    for (int pi = 0; pi < 8; ++pi)
        #pragma unroll
        for (int j = 0; j < 4; ++j) acc[pi][j] = 0.f;

    int cc = 0;
    for (; cc < C2 - 4; cc += 4) {
        ROWF(aA0, aA1, f0); LDA(aA0, aA1, cc + 4); LDF(f0, cc + 4);
        ROWF(aB0, aB1, f1); LDA(aB0, aB1, cc + 5); LDF(f1, cc + 5);
        ROWF(aC0, aC1, f2); LDA(aC0, aC1, cc + 6); LDF(f2, cc + 6);
        ROWF(aD0, aD1, f3); LDA(aD0, aD1, cc + 7); LDF(f3, cc + 7);
    }
    ROWF(aA0, aA1, f0); ROWF(aB0, aB1, f1);
    ROWF(aC0, aC1, f2); ROWF(aD0, aD1, f3);

    float best[8];
    int   bq[8];
    #pragma unroll
    for (int pi = 0; pi < 8; ++pi) { best[pi] = -INFINITY; bq[pi] = 0x7FFFFFFF; }

    #pragma unroll
    for (int j = 0; j < 4; ++j) {
        int k = koff + j;
        if (k >= n0) continue;
        float sc = invc[b * HW + k];
        int   q  = q0[k];
        #pragma unroll
        for (int pi = 0; pi < 8; ++pi) {
            float cv = acc[pi][j] * sc;
            if (cv > best[pi] || (cv == best[pi] && q < bq[pi])) {
                best[pi] = cv; bq[pi] = q;
            }
        }
    }

    // wave reduce (all 64 lanes of this wave share the same 8 p's)
    #pragma unroll
    for (int m = 1; m < 64; m <<= 1) {
        #pragma unroll
        for (int pi = 0; pi < 8; ++pi) {
            float ov = __shfl_xor(best[pi], m);
            int   oq = __shfl_xor(bq[pi], m);
            if (ov > best[pi] || (ov == best[pi] && oq < bq[pi])) {
                best[pi] = ov; bq[pi] = oq;
            }
        }
    }
    if (lane == 0) {
        #pragma unroll
        for (int pi = 0; pi < 8; ++pi) {
            int pidx = tile * 8 + pi;
            int p = (pidx < n1) ? p1[pidx] : -1;
            if (p >= 0)
                atomicMax(&packed[(size_t)b * HW + p], mkkey(best[pi], (unsigned)bq[pi]));
        }
    }
}

// --- 4. shift writeback with inline decode:
//     out[b, 512+c, p] = flag[p] ? lf[b, c, argmax_q(packed)] : 0
//     (fully overwrites the lfc/ffc scratch region — must run after argmax)
__global__ void shift_kernel(const float* __restrict__ x, const int* __restrict__ flag,
                             const unsigned long long* __restrict__ packed,
                             float* __restrict__ out) {
    int cc = blockIdx.x, b = blockIdx.y;
    const float* lfrow = x + ((size_t)b * NC + C2 + cc) * HW;
    float*       orow  = out + ((size_t)b * 768 + 512 + cc) * HW;
    const unsigned long long* pk = packed + (size_t)b * HW;
    for (int p = threadIdx.x; p < HW; p += 256) {
        float v = 0.f;
        if (flag[p] == 1) {
            unsigned low = (unsigned)(pk[p] & 0xFFFFFFFFull);
            int q = (int)((0xFFFFFFFFu - low) & (HW - 1));
            v = lfrow[q];
        }
        orow[p] = v;
    }
}

extern "C" void kernel_launch(void* const* d_in, const int* in_sizes, int n_in,
                              void* d_out, int out_size, void* d_ws, size_t ws_size,
                              hipStream_t stream) {
    const float* x    = (const float*)d_in[0];
    const int*   flag = (const int*)d_in[1];
    float*       out  = (float*)d_out;
    char*        ws   = (char*)d_ws;

    unsigned long long* packed = (unsigned long long*)(ws + WS_PACKED);
    int*   q0   = (int*)(ws + WS_Q0);
    int*   p1   = (int*)(ws + WS_P1);
    int*   cnt  = (int*)(ws + WS_CNT);
    float* invc = (float*)(ws + WS_INVC);

    hipMemsetAsync(packed, 0, (size_t)NB * HW * sizeof(unsigned long long), stream);

    compact_kernel<<<1, 256, 0, stream>>>(flag, q0, p1, cnt);
    pack_kernel<<<dim3(HW / 256, NC, NB), 256, 0, stream>>>(x, q0, p1, cnt, out);
    invc_kernel<<<dim3(HW / 256, NB), 256, 0, stream>>>(out, cnt, invc);
    argmax_kernel<<<dim3(NB * NT1 * NPR), 128, 0, stream>>>(out, invc, q0, p1, cnt, packed);
    shift_kernel<<<dim3(C2, NB), 256, 0, stream>>>(x, flag, packed, out);
}

// Round 16
// 253.183 us; speedup vs baseline: 1.4321x; 1.0332x over previous
//
#include <hip/hip_runtime.h>
#include <stdint.h>
#include <math.h>

#define HW   4096
#define NB   8
#define NC   512
#define C2   256
#define QC   256    // q-chunk per wave (4 k per lane via one float4)
#define NT16 64     // p-tiles of 16 (n1 = 1024 for this fixed flag)
#define NPR  6      // chunk-pairs (12 chunks / 2 waves); dead waves exit

// ---------- ws layout (bytes) ----------
#define WS_PACKED 0         // u64 packed[8*4096]            = 262144
#define WS_Q0     393216    // i32 q0list[4096]              = 16384
#define WS_P1     409600    // i32 p1list[4096]              = 16384
#define WS_CNT    425984    // i32 cnt[2]
#define WS_INVC   558080    // f32 invc[8*4096]              = 131072

__device__ __forceinline__ unsigned long long mkkey(float v, unsigned q) {
    unsigned u = __float_as_uint(v);
    u = (u & 0x80000000u) ? ~u : (u | 0x80000000u);   // monotone float -> u32
    return ((unsigned long long)u << 32) | (unsigned long long)(0xFFFFFFFFu - q);
}

// Packed scratch lives in d_out's shift region (channels [512,768) of batch b)
// = 1M floats per batch: lfc (C2 x ns) then ffc (C2 x ms). Written by
// pack_kernel, read by invc/argmax, then fully overwritten by shift_kernel.
__device__ __forceinline__ float* lfc_region(float* out, int b) {
    return out + ((size_t)b * 768 + 512) * HW;
}

// --- 1. deterministic sorted compaction of flag into p1 (flag==1) / q0 (flag==0)
__global__ void compact_kernel(const int* __restrict__ flag, int* __restrict__ q0,
                               int* __restrict__ p1, int* __restrict__ cnt) {
    __shared__ int c1s[256];
    int t = threadIdx.x;
    int f[16]; int n1 = 0;
    #pragma unroll
    for (int j = 0; j < 16; ++j) { f[j] = flag[t*16 + j]; n1 += (f[j] == 1); }
    c1s[t] = n1;
    __syncthreads();
    if (t == 0) {
        int run = 0;
        for (int i = 0; i < 256; ++i) { int v = c1s[i]; c1s[i] = run; run += v; }
        cnt[0] = run;          // n1
        cnt[1] = HW - run;     // n0
    }
    __syncthreads();
    int b1 = c1s[t];
    int b0 = t*16 - c1s[t];
    for (int j = 0; j < 16; ++j) {
        int i = t*16 + j;
        if (f[j] == 1) p1[b1++] = i; else q0[b0++] = i;
    }
}

// --- 2. fused copy + pack. Block (b, cy) reads row x[b][cy] once:
//     - coalesced copy: out[b][cy][i] = x[b][cy][i]
//     - cy <  256 (former): ffc[cy][m] = xrow[p1[m]]
//     - cy >= 256 (latter): lfc[cy-256][k] = xrow[q0[k]]
__global__ void pack_kernel(const float* __restrict__ x,
                            const int* __restrict__ q0, const int* __restrict__ p1,
                            const int* __restrict__ cnt, float* __restrict__ out) {
    int b = blockIdx.z, cy = blockIdx.y;
    int i = blockIdx.x * 256 + threadIdx.x;
    int n1 = cnt[0], n0 = cnt[1];
    int ns = (n0 + 3) & ~3, ms = (n1 + 3) & ~3;
    const float* xrow = x + ((size_t)b * NC + cy) * HW;
    out[((size_t)b * 768 + cy) * HW + i] = xrow[i];      // fused copy
    if (cy < C2) {
        if (i < n1) {
            float* ffc = lfc_region(out, b) + (size_t)C2 * ns;
            ffc[(size_t)cy * ms + i] = xrow[p1[i]];
        }
    } else {
        int c = cy - C2;
        if (i < n0) {
            float* lfc = lfc_region(out, b);
            lfc[(size_t)c * ns + i] = xrow[q0[i]];
        }
    }
}

// --- 2b. invc from packed lfc (coalesced; same c-ascending fp32 sum order
//     as the original norm kernel -> bit-identical values at q0 columns)
__global__ void invc_kernel(const float* __restrict__ out, const int* __restrict__ cnt,
                            float* __restrict__ invc) {
    int b = blockIdx.y;
    int n0 = cnt[1];
    int ns = (n0 + 3) & ~3;
    int k = blockIdx.x * 256 + threadIdx.x;
    if (k >= n0) return;
    const float* lfc = lfc_region((float*)out, b) + k;
    float s = 0.f;
    #pragma unroll 8
    for (int c = 0; c < C2; ++c) {
        float v = lfc[(size_t)c * ns];
        s = fmaf(v, v, s);
    }
    invc[b * HW + k] = 1.0f / fmaxf(sqrtf(s), 1e-8f);
}

// one c-row of FMAs: 16 p (wave-uniform, SGPR) x 4 k (per-lane float4 F)
#define ROWF(Aa, Ab, Ac, Ad, F) {                                         \
    float av[16] = {Aa.x, Aa.y, Aa.z, Aa.w, Ab.x, Ab.y, Ab.z, Ab.w,       \
                    Ac.x, Ac.y, Ac.z, Ac.w, Ad.x, Ad.y, Ad.z, Ad.w};      \
    float bv[4] = {F.x, F.y, F.z, F.w};                                   \
    _Pragma("unroll")                                                     \
    for (int pi = 0; pi < 16; ++pi) {                                     \
        _Pragma("unroll")                                                 \
        for (int j = 0; j < 4; ++j)                                       \
            acc[pi][j] = fmaf(av[pi], bv[j], acc[pi][j]);                 \
    } }

// ff: block-uniform base -> scalar s_loads (zero VALU); 16 floats per row
#define LDA(Aa, Ab, Ac, Ad, C) { const float* fa_ = fb + (size_t)(C) * ms; \
    Aa = *(const float4*)fa_;        Ab = *(const float4*)(fa_ + 4);      \
    Ac = *(const float4*)(fa_ + 8);  Ad = *(const float4*)(fa_ + 12); }
// lf: UNIFORM row pointer + constant per-lane 32-bit offset -> saddr-form
// global_load, row advance on the scalar pipe
#define LDF(F, C) { const float* rp_ = lfc + (size_t)(C) * ns;            \
    F = *(const float4*)(rp_ + koff); }

// --- 3. cos + argmax, LDS-free, 16-p register tile.
//     R15 post-mortem: lf L2 traffic = 3.2 GB / 186us ~ 17 TB/s ~ 50% of
//     the 34.5 TB/s L2 ceiling -> L2-BW co-limited (occupancy pinned ~48%
//     across block shapes, VALU-busy flat at ~143us). Fix: p-tile 16 ->
//     the same 16B lf float4 feeds 64 FMA instead of 32; lf traffic /2.
//     ff stays on the scalar pipe (tile from blockIdx ONLY — R14 lesson:
//     threadIdx-dependent tile kills s_load), 4x s_load_dwordx4 per row,
//     depth-2 E/O prefetch (SGPR cap 102); lf keeps depth-4 float4.
//     2 waves/block: same tile, different chunk. bid&7 = batch -> XCD pin
//     (4MB lfc+ffc per batch in one XCD L2; R9: FETCH 148->16.6MB).
//     NOTE: no min-waves clamp in launch_bounds — (256,4) forced VGPR=64
//     and spilled acc to scratch (13 GB HBM, 7x regression in R3).
__global__ void __launch_bounds__(128) argmax_kernel(
        float* __restrict__ out, const float* __restrict__ invc,
        const int* __restrict__ q0, const int* __restrict__ p1,
        const int* __restrict__ cnt, unsigned long long* __restrict__ packed) {
    int bid   = blockIdx.x;
    int b     = bid & 7;
    int s     = bid >> 3;
    int tile  = s & (NT16 - 1);         // blockIdx-only -> wave-uniform
    int pair  = s >> 6;
    int n1 = cnt[0], n0 = cnt[1];
    if (tile * 16 >= n1) return;
    int wid  = threadIdx.x >> 6;        // 0..1
    int lane = threadIdx.x & 63;
    int chunk = pair * 2 + wid;
    if (chunk * QC >= n0) return;       // per-wave exit; no barriers anywhere
    int ns = (n0 + 3) & ~3, ms = (n1 + 3) & ~3;

    const float* lfc = lfc_region(out, b);
    const float* ffc = lfc + (size_t)C2 * ns;
    int koff = chunk * QC + lane * 4;   // element offset, constant per lane

    const float* fb = ffc + tile * 16;  // block-uniform base

    float4 eA, eB, eC, eD;              // ff row (even slot)
    float4 oA, oB, oC, oD;              // ff row (odd slot)
    float4 f0, f1, f2, f3;              // lf rows, depth 4
    LDA(eA, eB, eC, eD, 0)
    LDA(oA, oB, oC, oD, 1)
    LDF(f0, 0) LDF(f1, 1) LDF(f2, 2) LDF(f3, 3)

    float acc[16][4];
    #pragma unroll
    for (int pi = 0; pi < 16; ++pi)
        #pragma unroll
        for (int j = 0; j < 4; ++j) acc[pi][j] = 0.f;

    // invariant at loop head: e=row cc, o=row cc+1, f0..f3 = rows cc..cc+3
    int cc = 0;
    for (; cc < C2 - 4; cc += 4) {
        ROWF(eA, eB, eC, eD, f0); LDA(eA, eB, eC, eD, cc + 2); LDF(f0, cc + 4);
        ROWF(oA, oB, oC, oD, f1); LDA(oA, oB, oC, oD, cc + 3); LDF(f1, cc + 5);
        ROWF(eA, eB, eC, eD, f2); LDA(eA, eB, eC, eD, cc + 4); LDF(f2, cc + 6);
        ROWF(oA, oB, oC, oD, f3); LDA(oA, oB, oC, oD, cc + 5); LDF(f3, cc + 7);
    }
    // cc = 252: e=252, o=253, f0..f3 = 252..255; no prefetch past row 255
    ROWF(eA, eB, eC, eD, f0); LDA(eA, eB, eC, eD, 254);
    ROWF(oA, oB, oC, oD, f1); LDA(oA, oB, oC, oD, 255);
    ROWF(eA, eB, eC, eD, f2);
    ROWF(oA, oB, oC, oD, f3);

    float best[16];
    int   bq[16];
    #pragma unroll
    for (int pi = 0; pi < 16; ++pi) { best[pi] = -INFINITY; bq[pi] = 0x7FFFFFFF; }

    #pragma unroll
    for (int j = 0; j < 4; ++j) {
        int k = koff + j;
        if (k >= n0) continue;
        float sc = invc[b * HW + k];
        int   q  = q0[k];
        #pragma unroll
        for (int pi = 0; pi < 16; ++pi) {
            float cv = acc[pi][j] * sc;
            if (cv > best[pi] || (cv == best[pi] && q < bq[pi])) {
                best[pi] = cv; bq[pi] = q;
            }
        }
    }

    // wave reduce (all 64 lanes of this wave share the same 16 p's)
    #pragma unroll
    for (int m = 1; m < 64; m <<= 1) {
        #pragma unroll
        for (int pi = 0; pi < 16; ++pi) {
            float ov = __shfl_xor(best[pi], m);
            int   oq = __shfl_xor(bq[pi], m);
            if (ov > best[pi] || (ov == best[pi] && oq < bq[pi])) {
                best[pi] = ov; bq[pi] = oq;
            }
        }
    }
    if (lane == 0) {
        #pragma unroll
        for (int pi = 0; pi < 16; ++pi) {
            int pidx = tile * 16 + pi;
            int p = (pidx < n1) ? p1[pidx] : -1;
            if (p >= 0)
                atomicMax(&packed[(size_t)b * HW + p], mkkey(best[pi], (unsigned)bq[pi]));
        }
    }
}

// --- 4. shift writeback with inline decode:
//     out[b, 512+c, p] = flag[p] ? lf[b, c, argmax_q(packed)] : 0
//     (fully overwrites the lfc/ffc scratch region — must run after argmax)
__global__ void shift_kernel(const float* __restrict__ x, const int* __restrict__ flag,
                             const unsigned long long* __restrict__ packed,
                             float* __restrict__ out) {
    int cc = blockIdx.x, b = blockIdx.y;
    const float* lfrow = x + ((size_t)b * NC + C2 + cc) * HW;
    float*       orow  = out + ((size_t)b * 768 + 512 + cc) * HW;
    const unsigned long long* pk = packed + (size_t)b * HW;
    for (int p = threadIdx.x; p < HW; p += 256) {
        float v = 0.f;
        if (flag[p] == 1) {
            unsigned low = (unsigned)(pk[p] & 0xFFFFFFFFull);
            int q = (int)((0xFFFFFFFFu - low) & (HW - 1));
            v = lfrow[q];
        }
        orow[p] = v;
    }
}

extern "C" void kernel_launch(void* const* d_in, const int* in_sizes, int n_in,
                              void* d_out, int out_size, void* d_ws, size_t ws_size,
                              hipStream_t stream) {
    const float* x    = (const float*)d_in[0];
    const int*   flag = (const int*)d_in[1];
    float*       out  = (float*)d_out;
    char*        ws   = (char*)d_ws;

    unsigned long long* packed = (unsigned long long*)(ws + WS_PACKED);
    int*   q0   = (int*)(ws + WS_Q0);
    int*   p1   = (int*)(ws + WS_P1);
    int*   cnt  = (int*)(ws + WS_CNT);
    float* invc = (float*)(ws + WS_INVC);

    hipMemsetAsync(packed, 0, (size_t)NB * HW * sizeof(unsigned long long), stream);

    compact_kernel<<<1, 256, 0, stream>>>(flag, q0, p1, cnt);
    pack_kernel<<<dim3(HW / 256, NC, NB), 256, 0, stream>>>(x, q0, p1, cnt, out);
    invc_kernel<<<dim3(HW / 256, NB), 256, 0, stream>>>(out, cnt, invc);
    argmax_kernel<<<dim3(NB * NT16 * NPR), 128, 0, stream>>>(out, invc, q0, p1, cnt, packed);
    shift_kernel<<<dim3(C2, NB), 256, 0, stream>>>(x, flag, packed, out);
}